// Round 12
// baseline (425.387 us; speedup 1.0000x reference)
//
#include <hip/hip_runtime.h>

// B=16384, FEAT=1024, FD=256, M=4 nodes, H1=4x128 (concat->512), H2=1x256, OUT=8.
// Round 12 = round-11 resubmit (infra failure, kernel never ran): round-10
// verbatim + single-barrier double-buffered LDS in the GEMM. Math bit-identical
// to rounds 4/10.

typedef __attribute__((ext_vector_type(8))) _Float16 f16x8;
typedef __attribute__((ext_vector_type(4))) float f32x4;

struct P4 { const float* p[4]; };

__device__ __forceinline__ float sigmoidf_(float x) { return 1.0f / (1.0f + expf(-x)); }
__device__ __forceinline__ float gelu_(float x) {
    return 0.5f * x * (1.0f + erff(x * 0.70710678118654752440f));
}

// ---------------- fp16-MFMA NT GEMM: C[M,N] = act(A[M,K] @ Bw[N,K]^T + bias) -
// fp32 in memory, converted to fp16 during LDS staging; fp32 accumulate.
// BM=BN=128, BK=32, 256 threads = 4 waves (2x2), each wave owns 64x64 out.
// Double-buffered LDS, one barrier per K-iteration:
//   iter k: [issue loads k+1] -> MFMA on buf[cur] -> [store k+1 -> buf[cur^1]]
//           -> barrier -> cur ^= 1
template<int ACT, bool HAS_BIAS>
__global__ __launch_bounds__(256)
void gemm_nt_mfma(P4 A4, P4 W4, P4 b4, float* __restrict__ C,
                  int K, int lda, int ldc, int zofs)
{
    __shared__ __align__(16) _Float16 As[2][128][32];
    __shared__ __align__(16) _Float16 Bs[2][128][32];
    const int z = blockIdx.z;
    const float* __restrict__ A    = A4.p[z];
    const float* __restrict__ Bw   = W4.p[z];
    const float* __restrict__ bias = b4.p[z];
    float* __restrict__ Cz = C + (long)z * zofs;

    const int t    = threadIdx.x;
    const int lane = t & 63;
    const int w    = t >> 6;
    const int wr   = (w >> 1) << 6;     // wave row base (0/64)
    const int wc   = (w & 1) << 6;      // wave col base (0/64)
    const long rowA = (long)blockIdx.y * 128;
    const long colB = (long)blockIdx.x * 128;

    // per-thread staging addresses: slot f = t + i*256 -> row f>>3, col (f&7)*4
    const float* Apt[4];
    const float* Bpt[4];
    int rr[4], cc[4];
    #pragma unroll
    for (int i = 0; i < 4; ++i) {
        const int f = t + i * 256;
        rr[i] = f >> 3;
        cc[i] = (f & 7) << 2;
        Apt[i] = A  + (rowA + rr[i]) * (long)lda + cc[i];
        Bpt[i] = Bw + (colB + rr[i]) * (long)K   + cc[i];
    }

    f32x4 acc[4][4] = {};

    // prologue: load tile 0, store to buffer 0
    float4 areg[4], breg[4];
    #pragma unroll
    for (int i = 0; i < 4; ++i) {
        areg[i] = *(const float4*)(Apt[i]);
        breg[i] = *(const float4*)(Bpt[i]);
    }
    #pragma unroll
    for (int i = 0; i < 4; ++i) {
        union { _Float16 h[4]; uint2 u; } pa, pb;
        pa.h[0] = (_Float16)areg[i].x; pa.h[1] = (_Float16)areg[i].y;
        pa.h[2] = (_Float16)areg[i].z; pa.h[3] = (_Float16)areg[i].w;
        pb.h[0] = (_Float16)breg[i].x; pb.h[1] = (_Float16)breg[i].y;
        pb.h[2] = (_Float16)breg[i].z; pb.h[3] = (_Float16)breg[i].w;
        *(uint2*)&As[0][rr[i]][cc[i]] = pa.u;
        *(uint2*)&Bs[0][rr[i]][cc[i]] = pb.u;
    }
    __syncthreads();

    const int fr = lane & 15;
    const int fg = (lane >> 4) << 3;
    int cur = 0;

    for (int k0 = 0; k0 < K; k0 += 32) {
        const int kn = k0 + 32;
        // ---- issue next tile's global loads (latency hides under MFMA) ----
        if (kn < K) {
            #pragma unroll
            for (int i = 0; i < 4; ++i) {
                areg[i] = *(const float4*)(Apt[i] + kn);
                breg[i] = *(const float4*)(Bpt[i] + kn);
            }
        }

        // ---- fragments + MFMA on buf[cur] ----
        f16x8 af[4], bf[4];
        #pragma unroll
        for (int m = 0; m < 4; ++m) af[m] = *(const f16x8*)&As[cur][wr + m*16 + fr][fg];
        #pragma unroll
        for (int n = 0; n < 4; ++n) bf[n] = *(const f16x8*)&Bs[cur][wc + n*16 + fr][fg];
        #pragma unroll
        for (int m = 0; m < 4; ++m)
            #pragma unroll
            for (int n = 0; n < 4; ++n)
                acc[m][n] = __builtin_amdgcn_mfma_f32_16x16x32_f16(af[m], bf[n], acc[m][n], 0, 0, 0);

        // ---- store next tile into the other buffer ----
        if (kn < K) {
            const int nxt = cur ^ 1;
            #pragma unroll
            for (int i = 0; i < 4; ++i) {
                union { _Float16 h[4]; uint2 u; } pa, pb;
                pa.h[0] = (_Float16)areg[i].x; pa.h[1] = (_Float16)areg[i].y;
                pa.h[2] = (_Float16)areg[i].z; pa.h[3] = (_Float16)areg[i].w;
                pb.h[0] = (_Float16)breg[i].x; pb.h[1] = (_Float16)breg[i].y;
                pb.h[2] = (_Float16)breg[i].z; pb.h[3] = (_Float16)breg[i].w;
                *(uint2*)&As[nxt][rr[i]][cc[i]] = pa.u;
                *(uint2*)&Bs[nxt][rr[i]][cc[i]] = pb.u;
            }
        }
        __syncthreads();
        cur ^= 1;
    }

    // ---- epilogue: C/D layout col = lane&15, row = (lane>>4)*4 + j ----
    const int fq = lane >> 4;
    #pragma unroll
    for (int n = 0; n < 4; ++n) {
        const long col = colB + wc + n*16 + fr;
        const float bn = HAS_BIAS ? bias[col] : 0.0f;
        #pragma unroll
        for (int m = 0; m < 4; ++m) {
            const long row0 = rowA + wr + m*16 + fq*4;
            #pragma unroll
            for (int j = 0; j < 4; ++j) {
                float x = acc[m][n][j] + bn;
                if (ACT == 1) x = fmaxf(x, 0.0f);
                Cz[(row0 + j) * (long)ldc + col] = x;
            }
        }
    }
}

// ---------------- GAT1 attention (round-4 verbatim): one wave per (b,h) -----
__global__ __launch_bounds__(256)
void gat1_attn_kernel(float* __restrict__ h1,
                      const int* __restrict__ missing,
                      const float* __restrict__ attl, const float* __restrict__ attr,
                      const float* __restrict__ bias)
{
    const int gtid = blockIdx.x * 256 + threadIdx.x;
    const int wid  = gtid >> 6;
    const int lane = threadIdx.x & 63;
    const int b = wid >> 2;
    const int h = wid & 3;
    const int cb = h * 128 + lane;
    float* base = h1 + (size_t)b * 2048 + cb;

    float hr[4][2];
    #pragma unroll
    for (int j = 0; j < 4; ++j) { hr[j][0] = base[j*512]; hr[j][1] = base[j*512 + 64]; }
    const float al0 = attl[cb], al1 = attl[cb+64];
    const float ar0 = attr[cb], ar1 = attr[cb+64];

    float red[24];
    #pragma unroll
    for (int i = 0; i < 4; ++i)
        #pragma unroll
        for (int j = 0; j < 4; ++j)
            red[i*4+j] = hr[i][0]*hr[j][0] + hr[i][1]*hr[j][1];
    #pragma unroll
    for (int j = 0; j < 4; ++j) {
        red[16+j] = hr[j][0]*al0 + hr[j][1]*al1;
        red[20+j] = hr[j][0]*ar0 + hr[j][1]*ar1;
    }
    #pragma unroll
    for (int m = 1; m < 64; m <<= 1)
        #pragma unroll
        for (int r = 0; r < 24; ++r)
            red[r] += __shfl_xor(red[r], m, 64);

    const int miss = missing[b];
    bool pres[4];
    #pragma unroll
    for (int mm = 0; mm < 4; ++mm) pres[mm] = (miss != mm + 1);

    float attn[4][4];
    #pragma unroll
    for (int i = 0; i < 4; ++i) {
        float av[4]; float mx = -3.4e38f;
        #pragma unroll
        for (int j = 0; j < 4; ++j) {
            const bool mk = (i == j) || (pres[i] && pres[j]);
            float v = (red[20+i] + red[16+j]) * sigmoidf_(red[i*4+j]);
            v = (v >= 0.0f) ? v : 0.2f * v;
            av[j] = mk ? v : -1e30f;
            mx = fmaxf(mx, av[j]);
        }
        float den = 0.0f;
        #pragma unroll
        for (int j = 0; j < 4; ++j) { av[j] = expf(av[j] - mx); den += av[j]; }
        const float inv = 1.0f / den;
        #pragma unroll
        for (int j = 0; j < 4; ++j) attn[i][j] = av[j] * inv;
    }

    const float b0 = bias[cb], b1 = bias[cb+64];
    #pragma unroll
    for (int i = 0; i < 4; ++i) {
        float o0 = b0, o1 = b1;
        #pragma unroll
        for (int j = 0; j < 4; ++j) { o0 += attn[i][j]*hr[j][0]; o1 += attn[i][j]*hr[j][1]; }
        base[i*512]      = gelu_(o0);
        base[i*512 + 64] = gelu_(o1);
    }
}

// ------- GAT2 attention + node-mean pool + LayerNorm (round-4 verbatim) ------
__global__ __launch_bounds__(256)
void gat2_attn_kernel(const float* __restrict__ h2,
                      const int* __restrict__ missing,
                      const float* __restrict__ attl, const float* __restrict__ attr,
                      const float* __restrict__ bias,
                      const float* __restrict__ lng, const float* __restrict__ lnb,
                      float* __restrict__ normed)
{
    const int gtid = blockIdx.x * 256 + threadIdx.x;
    const int b = gtid >> 6;
    const int lane = threadIdx.x & 63;
    const float4* hp = (const float4*)(h2 + (size_t)b * 1024);

    float4 hr[4];
    #pragma unroll
    for (int j = 0; j < 4; ++j) hr[j] = hp[j*64 + lane];
    const float4 al = ((const float4*)attl)[lane];
    const float4 ar = ((const float4*)attr)[lane];

    float red[24];
    #pragma unroll
    for (int i = 0; i < 4; ++i)
        #pragma unroll
        for (int j = 0; j < 4; ++j)
            red[i*4+j] = hr[i].x*hr[j].x + hr[i].y*hr[j].y + hr[i].z*hr[j].z + hr[i].w*hr[j].w;
    #pragma unroll
    for (int j = 0; j < 4; ++j) {
        red[16+j] = hr[j].x*al.x + hr[j].y*al.y + hr[j].z*al.z + hr[j].w*al.w;
        red[20+j] = hr[j].x*ar.x + hr[j].y*ar.y + hr[j].z*ar.z + hr[j].w*ar.w;
    }
    #pragma unroll
    for (int m = 1; m < 64; m <<= 1)
        #pragma unroll
        for (int r = 0; r < 24; ++r)
            red[r] += __shfl_xor(red[r], m, 64);

    const int miss = missing[b];
    bool pres[4];
    #pragma unroll
    for (int mm = 0; mm < 4; ++mm) pres[mm] = (miss != mm + 1);

    float wsum[4] = {0.f, 0.f, 0.f, 0.f};
    #pragma unroll
    for (int i = 0; i < 4; ++i) {
        float av[4]; float mx = -3.4e38f;
        #pragma unroll
        for (int j = 0; j < 4; ++j) {
            const bool mk = (i == j) || (pres[i] && pres[j]);
            float v = (red[20+i] + red[16+j]) * sigmoidf_(red[i*4+j]);
            v = (v >= 0.0f) ? v : 0.2f * v;
            av[j] = mk ? v : -1e30f;
            mx = fmaxf(mx, av[j]);
        }
        float den = 0.0f;
        #pragma unroll
        for (int j = 0; j < 4; ++j) { av[j] = expf(av[j] - mx); den += av[j]; }
        const float inv = 0.25f / den;
        #pragma unroll
        for (int j = 0; j < 4; ++j) wsum[j] += av[j] * inv;
    }

    const float4 bv = ((const float4*)bias)[lane];
    float pooled[4] = {bv.x, bv.y, bv.z, bv.w};
    #pragma unroll
    for (int j = 0; j < 4; ++j) {
        pooled[0] += wsum[j] * hr[j].x;
        pooled[1] += wsum[j] * hr[j].y;
        pooled[2] += wsum[j] * hr[j].z;
        pooled[3] += wsum[j] * hr[j].w;
    }

    float s1 = pooled[0] + pooled[1] + pooled[2] + pooled[3];
    float s2 = pooled[0]*pooled[0] + pooled[1]*pooled[1] + pooled[2]*pooled[2] + pooled[3]*pooled[3];
    #pragma unroll
    for (int m = 1; m < 64; m <<= 1) {
        s1 += __shfl_xor(s1, m, 64);
        s2 += __shfl_xor(s2, m, 64);
    }
    const float mu   = s1 * (1.0f / 256.0f);
    const float var  = s2 * (1.0f / 256.0f) - mu * mu;
    const float rstd = rsqrtf(var + 1e-5f);
    const float4 g  = ((const float4*)lng)[lane];
    const float4 bb = ((const float4*)lnb)[lane];
    float4 o;
    o.x = (pooled[0] - mu) * rstd * g.x + bb.x;
    o.y = (pooled[1] - mu) * rstd * g.y + bb.y;
    o.z = (pooled[2] - mu) * rstd * g.z + bb.z;
    o.w = (pooled[3] - mu) * rstd * g.w + bb.w;
    ((float4*)normed)[(size_t)b * 64 + lane] = o;
}

// ---------------- head2 (round-4 verbatim) ----------------------------------
__global__ __launch_bounds__(256)
void head2_kernel(const float* __restrict__ hid, const float* __restrict__ W2,
                  const float* __restrict__ b2, float* __restrict__ out)
{
    const int t = blockIdx.x * 256 + threadIdx.x;
    const int b = t >> 3, o = t & 7;
    const float4* hp = (const float4*)(hid + (size_t)b * 256);
    const float4* wp = (const float4*)(W2 + o * 256);
    float acc = b2[o];
    #pragma unroll 8
    for (int c = 0; c < 64; ++c) {
        const float4 hv = hp[c], wv = wp[c];
        acc += hv.x*wv.x + hv.y*wv.y + hv.z*wv.z + hv.w*wv.w;
    }
    out[t] = acc;
}

// ---------------- launch (round-4 verbatim) ---------------------------------
extern "C" void kernel_launch(void* const* d_in, const int* in_sizes, int n_in,
                              void* d_out, int out_size, void* d_ws, size_t ws_size,
                              hipStream_t stream)
{
    (void)in_sizes; (void)n_in; (void)out_size; (void)ws_size;
    const float* X0 = (const float*)d_in[0];
    const float* X1 = (const float*)d_in[1];
    const float* X2 = (const float*)d_in[2];
    const float* X3 = (const float*)d_in[3];
    const int*   miss  = (const int*)d_in[4];
    const float* g1_W  = (const float*)d_in[13];
    const float* g1_al = (const float*)d_in[14];
    const float* g1_ar = (const float*)d_in[15];
    const float* g1_b  = (const float*)d_in[16];
    const float* g2_W  = (const float*)d_in[17];
    const float* g2_al = (const float*)d_in[18];
    const float* g2_ar = (const float*)d_in[19];
    const float* g2_b  = (const float*)d_in[20];
    const float* ln_g  = (const float*)d_in[21];
    const float* ln_b  = (const float*)d_in[22];
    const float* h_W1  = (const float*)d_in[23];
    const float* h_b1  = (const float*)d_in[24];
    const float* h_W2  = (const float*)d_in[25];
    const float* h_b2  = (const float*)d_in[26];
    float* out = (float*)d_out;

    // workspace (fp32 elems), round-4 verbatim:
    float* ws     = (float*)d_ws;
    float* feats  = ws;
    float* h1     = ws + 16777216;
    float* h2     = ws;
    float* normed = ws + 16777216;
    float* hid    = normed + 4194304;

    const dim3 blk(256);

    P4 Xs  = {{X0, X1, X2, X3}};
    P4 Wms = {{(const float*)d_in[5], (const float*)d_in[7],
               (const float*)d_in[9], (const float*)d_in[11]}};
    P4 bms = {{(const float*)d_in[6], (const float*)d_in[8],
               (const float*)d_in[10], (const float*)d_in[12]}};
    P4 F4  = {{feats, feats, feats, feats}};
    P4 G1W = {{g1_W, g1_W, g1_W, g1_W}};
    P4 H14 = {{h1, h1, h1, h1}};
    P4 G2W = {{g2_W, g2_W, g2_W, g2_W}};
    P4 N4  = {{normed, normed, normed, normed}};
    P4 HW1 = {{h_W1, h_W1, h_W1, h_W1}};
    P4 HB1 = {{h_b1, h_b1, h_b1, h_b1}};
    P4 NUL = {{nullptr, nullptr, nullptr, nullptr}};

    // 1) per-modality projections (z-batched): feats[B,4,256]
    gemm_nt_mfma<0, true><<<dim3(2, 128, 4), blk, 0, stream>>>(
        Xs, Wms, bms, feats, /*K=*/1024, /*lda=*/1024, /*ldc=*/1024, /*zofs=*/256);

    // 2) gat1 linear: h1[65536,512] = feats[65536,256] @ g1_W^T
    gemm_nt_mfma<0, false><<<dim3(4, 512, 1), blk, 0, stream>>>(
        F4, G1W, NUL, h1, 256, 256, 512, 0);

    // 3) gat1 attention + bias + gelu (in-place on h1)
    gat1_attn_kernel<<<dim3(16384), blk, 0, stream>>>(h1, miss, g1_al, g1_ar, g1_b);

    // 4) gat2 linear: h2[65536,256] = x1[65536,512] @ g2_W^T
    gemm_nt_mfma<0, false><<<dim3(2, 512, 1), blk, 0, stream>>>(
        H14, G2W, NUL, h2, 512, 512, 256, 0);

    // 5) gat2 attention + pool + layernorm -> normed[16384,256]
    gat2_attn_kernel<<<dim3(4096), blk, 0, stream>>>(
        h2, miss, g2_al, g2_ar, g2_b, ln_g, ln_b, normed);

    // 6) head1: hid = relu(normed @ h_W1^T + h_b1)
    gemm_nt_mfma<1, true><<<dim3(2, 128, 1), blk, 0, stream>>>(
        N4, HW1, HB1, hid, 256, 256, 256, 0);

    // 7) head2: out[16384,8]
    head2_kernel<<<dim3(512), blk, 0, stream>>>(hid, h_W2, h_b2, out);
}

// Round 13
// 405.512 us; speedup vs baseline: 1.0490x; 1.0490x over previous
//
#include <hip/hip_runtime.h>

// B=16384, FEAT=1024, FD=256, M=4 nodes, H1=4x128 (concat->512), H2=1x256, OUT=8.
// Round 13: round-12 base + ONE change in the GEMM K-loop: 2-ahead register
// prefetch with LDS-write-at-top (issue tile k+2's loads in iter k; ds_write
// tile k+1 at the TOP of iter k, so the vmcnt wait is a full iteration after
// issue). Double-buffered LDS, one barrier/iter. Math bit-identical to r4/10/12.

typedef __attribute__((ext_vector_type(8))) _Float16 f16x8;
typedef __attribute__((ext_vector_type(4))) float f32x4;

struct P4 { const float* p[4]; };

__device__ __forceinline__ float sigmoidf_(float x) { return 1.0f / (1.0f + expf(-x)); }
__device__ __forceinline__ float gelu_(float x) {
    return 0.5f * x * (1.0f + erff(x * 0.70710678118654752440f));
}

// ---------------- fp16-MFMA NT GEMM: C[M,N] = act(A[M,K] @ Bw[N,K]^T + bias) -
// fp32 in memory, converted to fp16 during LDS staging; fp32 accumulate.
// BM=BN=128, BK=32, 256 threads = 4 waves (2x2), each wave owns 64x64 out.
// Schedule per iter k: [ds_write tile k+1 (regs from iter k-1)] ->
//                      [issue loads tile k+2] -> [MFMA buf k] -> [barrier]
template<int ACT, bool HAS_BIAS>
__global__ __launch_bounds__(256)
void gemm_nt_mfma(P4 A4, P4 W4, P4 b4, float* __restrict__ C,
                  int K, int lda, int ldc, int zofs)
{
    __shared__ __align__(16) _Float16 As[2][128][32];
    __shared__ __align__(16) _Float16 Bs[2][128][32];
    const int z = blockIdx.z;
    const float* __restrict__ A    = A4.p[z];
    const float* __restrict__ Bw   = W4.p[z];
    const float* __restrict__ bias = b4.p[z];
    float* __restrict__ Cz = C + (long)z * zofs;

    const int t    = threadIdx.x;
    const int lane = t & 63;
    const int w    = t >> 6;
    const int wr   = (w >> 1) << 6;     // wave row base (0/64)
    const int wc   = (w & 1) << 6;      // wave col base (0/64)
    const long rowA = (long)blockIdx.y * 128;
    const long colB = (long)blockIdx.x * 128;

    // per-thread staging addresses: slot f = t + i*256 -> row f>>3, col (f&7)*4
    const float* Apt[4];
    const float* Bpt[4];
    int rr[4], cc[4];
    #pragma unroll
    for (int i = 0; i < 4; ++i) {
        const int f = t + i * 256;
        rr[i] = f >> 3;
        cc[i] = (f & 7) << 2;
        Apt[i] = A  + (rowA + rr[i]) * (long)lda + cc[i];
        Bpt[i] = Bw + (colB + rr[i]) * (long)K   + cc[i];
    }

    f32x4 acc[4][4] = {};
    const int NK = K >> 5;

    // prologue: tile 0 -> LDS buf0; tile 1 -> regs (aP/bP)
    float4 aP[4], bP[4], aN[4], bN[4];
    #pragma unroll
    for (int i = 0; i < 4; ++i) {
        aP[i] = *(const float4*)(Apt[i]);
        bP[i] = *(const float4*)(Bpt[i]);
    }
    #pragma unroll
    for (int i = 0; i < 4; ++i) {
        union { _Float16 h[4]; uint2 u; } pa, pb;
        pa.h[0] = (_Float16)aP[i].x; pa.h[1] = (_Float16)aP[i].y;
        pa.h[2] = (_Float16)aP[i].z; pa.h[3] = (_Float16)aP[i].w;
        pb.h[0] = (_Float16)bP[i].x; pb.h[1] = (_Float16)bP[i].y;
        pb.h[2] = (_Float16)bP[i].z; pb.h[3] = (_Float16)bP[i].w;
        *(uint2*)&As[0][rr[i]][cc[i]] = pa.u;
        *(uint2*)&Bs[0][rr[i]][cc[i]] = pb.u;
    }
    if (NK > 1) {
        #pragma unroll
        for (int i = 0; i < 4; ++i) {
            aP[i] = *(const float4*)(Apt[i] + 32);
            bP[i] = *(const float4*)(Bpt[i] + 32);
        }
    }
    __syncthreads();

    const int fr = lane & 15;
    const int fg = (lane >> 4) << 3;

    for (int kk = 0; kk < NK; ++kk) {
        const int cur = kk & 1, nxt = cur ^ 1;

        // 1) write tile kk+1 (regs loaded a full iteration ago) -> buf[nxt]
        if (kk + 1 < NK) {
            #pragma unroll
            for (int i = 0; i < 4; ++i) {
                union { _Float16 h[4]; uint2 u; } pa, pb;
                pa.h[0] = (_Float16)aP[i].x; pa.h[1] = (_Float16)aP[i].y;
                pa.h[2] = (_Float16)aP[i].z; pa.h[3] = (_Float16)aP[i].w;
                pb.h[0] = (_Float16)bP[i].x; pb.h[1] = (_Float16)bP[i].y;
                pb.h[2] = (_Float16)bP[i].z; pb.h[3] = (_Float16)bP[i].w;
                *(uint2*)&As[nxt][rr[i]][cc[i]] = pa.u;
                *(uint2*)&Bs[nxt][rr[i]][cc[i]] = pb.u;
            }
        }

        // 2) issue loads for tile kk+2 (consumed next iteration)
        if (kk + 2 < NK) {
            const int ko = (kk + 2) << 5;
            #pragma unroll
            for (int i = 0; i < 4; ++i) {
                aN[i] = *(const float4*)(Apt[i] + ko);
                bN[i] = *(const float4*)(Bpt[i] + ko);
            }
        }

        // 3) fragments + MFMA on buf[cur]
        f16x8 af[4], bf[4];
        #pragma unroll
        for (int m = 0; m < 4; ++m) af[m] = *(const f16x8*)&As[cur][wr + m*16 + fr][fg];
        #pragma unroll
        for (int n = 0; n < 4; ++n) bf[n] = *(const f16x8*)&Bs[cur][wc + n*16 + fr][fg];
        #pragma unroll
        for (int m = 0; m < 4; ++m)
            #pragma unroll
            for (int n = 0; n < 4; ++n)
                acc[m][n] = __builtin_amdgcn_mfma_f32_16x16x32_f16(af[m], bf[n], acc[m][n], 0, 0, 0);

        // 4) barrier; 5) roll prefetch regs
        __syncthreads();
        if (kk + 2 < NK) {
            #pragma unroll
            for (int i = 0; i < 4; ++i) { aP[i] = aN[i]; bP[i] = bN[i]; }
        }
    }

    // ---- epilogue: C/D layout col = lane&15, row = (lane>>4)*4 + j ----
    const int fq = lane >> 4;
    #pragma unroll
    for (int n = 0; n < 4; ++n) {
        const long col = colB + wc + n*16 + fr;
        const float bn = HAS_BIAS ? bias[col] : 0.0f;
        #pragma unroll
        for (int m = 0; m < 4; ++m) {
            const long row0 = rowA + wr + m*16 + fq*4;
            #pragma unroll
            for (int j = 0; j < 4; ++j) {
                float x = acc[m][n][j] + bn;
                if (ACT == 1) x = fmaxf(x, 0.0f);
                Cz[(row0 + j) * (long)ldc + col] = x;
            }
        }
    }
}

// ---------------- GAT1 attention (round-4 verbatim): one wave per (b,h) -----
__global__ __launch_bounds__(256)
void gat1_attn_kernel(float* __restrict__ h1,
                      const int* __restrict__ missing,
                      const float* __restrict__ attl, const float* __restrict__ attr,
                      const float* __restrict__ bias)
{
    const int gtid = blockIdx.x * 256 + threadIdx.x;
    const int wid  = gtid >> 6;
    const int lane = threadIdx.x & 63;
    const int b = wid >> 2;
    const int h = wid & 3;
    const int cb = h * 128 + lane;
    float* base = h1 + (size_t)b * 2048 + cb;

    float hr[4][2];
    #pragma unroll
    for (int j = 0; j < 4; ++j) { hr[j][0] = base[j*512]; hr[j][1] = base[j*512 + 64]; }
    const float al0 = attl[cb], al1 = attl[cb+64];
    const float ar0 = attr[cb], ar1 = attr[cb+64];

    float red[24];
    #pragma unroll
    for (int i = 0; i < 4; ++i)
        #pragma unroll
        for (int j = 0; j < 4; ++j)
            red[i*4+j] = hr[i][0]*hr[j][0] + hr[i][1]*hr[j][1];
    #pragma unroll
    for (int j = 0; j < 4; ++j) {
        red[16+j] = hr[j][0]*al0 + hr[j][1]*al1;
        red[20+j] = hr[j][0]*ar0 + hr[j][1]*ar1;
    }
    #pragma unroll
    for (int m = 1; m < 64; m <<= 1)
        #pragma unroll
        for (int r = 0; r < 24; ++r)
            red[r] += __shfl_xor(red[r], m, 64);

    const int miss = missing[b];
    bool pres[4];
    #pragma unroll
    for (int mm = 0; mm < 4; ++mm) pres[mm] = (miss != mm + 1);

    float attn[4][4];
    #pragma unroll
    for (int i = 0; i < 4; ++i) {
        float av[4]; float mx = -3.4e38f;
        #pragma unroll
        for (int j = 0; j < 4; ++j) {
            const bool mk = (i == j) || (pres[i] && pres[j]);
            float v = (red[20+i] + red[16+j]) * sigmoidf_(red[i*4+j]);
            v = (v >= 0.0f) ? v : 0.2f * v;
            av[j] = mk ? v : -1e30f;
            mx = fmaxf(mx, av[j]);
        }
        float den = 0.0f;
        #pragma unroll
        for (int j = 0; j < 4; ++j) { av[j] = expf(av[j] - mx); den += av[j]; }
        const float inv = 1.0f / den;
        #pragma unroll
        for (int j = 0; j < 4; ++j) attn[i][j] = av[j] * inv;
    }

    const float b0 = bias[cb], b1 = bias[cb+64];
    #pragma unroll
    for (int i = 0; i < 4; ++i) {
        float o0 = b0, o1 = b1;
        #pragma unroll
        for (int j = 0; j < 4; ++j) { o0 += attn[i][j]*hr[j][0]; o1 += attn[i][j]*hr[j][1]; }
        base[i*512]      = gelu_(o0);
        base[i*512 + 64] = gelu_(o1);
    }
}

// ------- GAT2 attention + node-mean pool + LayerNorm (round-4 verbatim) ------
__global__ __launch_bounds__(256)
void gat2_attn_kernel(const float* __restrict__ h2,
                      const int* __restrict__ missing,
                      const float* __restrict__ attl, const float* __restrict__ attr,
                      const float* __restrict__ bias,
                      const float* __restrict__ lng, const float* __restrict__ lnb,
                      float* __restrict__ normed)
{
    const int gtid = blockIdx.x * 256 + threadIdx.x;
    const int b = gtid >> 6;
    const int lane = threadIdx.x & 63;
    const float4* hp = (const float4*)(h2 + (size_t)b * 1024);

    float4 hr[4];
    #pragma unroll
    for (int j = 0; j < 4; ++j) hr[j] = hp[j*64 + lane];
    const float4 al = ((const float4*)attl)[lane];
    const float4 ar = ((const float4*)attr)[lane];

    float red[24];
    #pragma unroll
    for (int i = 0; i < 4; ++i)
        #pragma unroll
        for (int j = 0; j < 4; ++j)
            red[i*4+j] = hr[i].x*hr[j].x + hr[i].y*hr[j].y + hr[i].z*hr[j].z + hr[i].w*hr[j].w;
    #pragma unroll
    for (int j = 0; j < 4; ++j) {
        red[16+j] = hr[j].x*al.x + hr[j].y*al.y + hr[j].z*al.z + hr[j].w*al.w;
        red[20+j] = hr[j].x*ar.x + hr[j].y*ar.y + hr[j].z*ar.z + hr[j].w*ar.w;
    }
    #pragma unroll
    for (int m = 1; m < 64; m <<= 1)
        #pragma unroll
        for (int r = 0; r < 24; ++r)
            red[r] += __shfl_xor(red[r], m, 64);

    const int miss = missing[b];
    bool pres[4];
    #pragma unroll
    for (int mm = 0; mm < 4; ++mm) pres[mm] = (miss != mm + 1);

    float wsum[4] = {0.f, 0.f, 0.f, 0.f};
    #pragma unroll
    for (int i = 0; i < 4; ++i) {
        float av[4]; float mx = -3.4e38f;
        #pragma unroll
        for (int j = 0; j < 4; ++j) {
            const bool mk = (i == j) || (pres[i] && pres[j]);
            float v = (red[20+i] + red[16+j]) * sigmoidf_(red[i*4+j]);
            v = (v >= 0.0f) ? v : 0.2f * v;
            av[j] = mk ? v : -1e30f;
            mx = fmaxf(mx, av[j]);
        }
        float den = 0.0f;
        #pragma unroll
        for (int j = 0; j < 4; ++j) { av[j] = expf(av[j] - mx); den += av[j]; }
        const float inv = 0.25f / den;
        #pragma unroll
        for (int j = 0; j < 4; ++j) wsum[j] += av[j] * inv;
    }

    const float4 bv = ((const float4*)bias)[lane];
    float pooled[4] = {bv.x, bv.y, bv.z, bv.w};
    #pragma unroll
    for (int j = 0; j < 4; ++j) {
        pooled[0] += wsum[j] * hr[j].x;
        pooled[1] += wsum[j] * hr[j].y;
        pooled[2] += wsum[j] * hr[j].z;
        pooled[3] += wsum[j] * hr[j].w;
    }

    float s1 = pooled[0] + pooled[1] + pooled[2] + pooled[3];
    float s2 = pooled[0]*pooled[0] + pooled[1]*pooled[1] + pooled[2]*pooled[2] + pooled[3]*pooled[3];
    #pragma unroll
    for (int m = 1; m < 64; m <<= 1) {
        s1 += __shfl_xor(s1, m, 64);
        s2 += __shfl_xor(s2, m, 64);
    }
    const float mu   = s1 * (1.0f / 256.0f);
    const float var  = s2 * (1.0f / 256.0f) - mu * mu;
    const float rstd = rsqrtf(var + 1e-5f);
    const float4 g  = ((const float4*)lng)[lane];
    const float4 bb = ((const float4*)lnb)[lane];
    float4 o;
    o.x = (pooled[0] - mu) * rstd * g.x + bb.x;
    o.y = (pooled[1] - mu) * rstd * g.y + bb.y;
    o.z = (pooled[2] - mu) * rstd * g.z + bb.z;
    o.w = (pooled[3] - mu) * rstd * g.w + bb.w;
    ((float4*)normed)[(size_t)b * 64 + lane] = o;
}

// ---------------- head2 (round-4 verbatim) ----------------------------------
__global__ __launch_bounds__(256)
void head2_kernel(const float* __restrict__ hid, const float* __restrict__ W2,
                  const float* __restrict__ b2, float* __restrict__ out)
{
    const int t = blockIdx.x * 256 + threadIdx.x;
    const int b = t >> 3, o = t & 7;
    const float4* hp = (const float4*)(hid + (size_t)b * 256);
    const float4* wp = (const float4*)(W2 + o * 256);
    float acc = b2[o];
    #pragma unroll 8
    for (int c = 0; c < 64; ++c) {
        const float4 hv = hp[c], wv = wp[c];
        acc += hv.x*wv.x + hv.y*wv.y + hv.z*wv.z + hv.w*wv.w;
    }
    out[t] = acc;
}

// ---------------- launch (round-4 verbatim) ---------------------------------
extern "C" void kernel_launch(void* const* d_in, const int* in_sizes, int n_in,
                              void* d_out, int out_size, void* d_ws, size_t ws_size,
                              hipStream_t stream)
{
    (void)in_sizes; (void)n_in; (void)out_size; (void)ws_size;
    const float* X0 = (const float*)d_in[0];
    const float* X1 = (const float*)d_in[1];
    const float* X2 = (const float*)d_in[2];
    const float* X3 = (const float*)d_in[3];
    const int*   miss  = (const int*)d_in[4];
    const float* g1_W  = (const float*)d_in[13];
    const float* g1_al = (const float*)d_in[14];
    const float* g1_ar = (const float*)d_in[15];
    const float* g1_b  = (const float*)d_in[16];
    const float* g2_W  = (const float*)d_in[17];
    const float* g2_al = (const float*)d_in[18];
    const float* g2_ar = (const float*)d_in[19];
    const float* g2_b  = (const float*)d_in[20];
    const float* ln_g  = (const float*)d_in[21];
    const float* ln_b  = (const float*)d_in[22];
    const float* h_W1  = (const float*)d_in[23];
    const float* h_b1  = (const float*)d_in[24];
    const float* h_W2  = (const float*)d_in[25];
    const float* h_b2  = (const float*)d_in[26];
    float* out = (float*)d_out;

    // workspace (fp32 elems), round-4 verbatim:
    float* ws     = (float*)d_ws;
    float* feats  = ws;
    float* h1     = ws + 16777216;
    float* h2     = ws;
    float* normed = ws + 16777216;
    float* hid    = normed + 4194304;

    const dim3 blk(256);

    P4 Xs  = {{X0, X1, X2, X3}};
    P4 Wms = {{(const float*)d_in[5], (const float*)d_in[7],
               (const float*)d_in[9], (const float*)d_in[11]}};
    P4 bms = {{(const float*)d_in[6], (const float*)d_in[8],
               (const float*)d_in[10], (const float*)d_in[12]}};
    P4 F4  = {{feats, feats, feats, feats}};
    P4 G1W = {{g1_W, g1_W, g1_W, g1_W}};
    P4 H14 = {{h1, h1, h1, h1}};
    P4 G2W = {{g2_W, g2_W, g2_W, g2_W}};
    P4 N4  = {{normed, normed, normed, normed}};
    P4 HW1 = {{h_W1, h_W1, h_W1, h_W1}};
    P4 HB1 = {{h_b1, h_b1, h_b1, h_b1}};
    P4 NUL = {{nullptr, nullptr, nullptr, nullptr}};

    // 1) per-modality projections (z-batched): feats[B,4,256]
    gemm_nt_mfma<0, true><<<dim3(2, 128, 4), blk, 0, stream>>>(
        Xs, Wms, bms, feats, /*K=*/1024, /*lda=*/1024, /*ldc=*/1024, /*zofs=*/256);

    // 2) gat1 linear: h1[65536,512] = feats[65536,256] @ g1_W^T
    gemm_nt_mfma<0, false><<<dim3(4, 512, 1), blk, 0, stream>>>(
        F4, G1W, NUL, h1, 256, 256, 512, 0);

    // 3) gat1 attention + bias + gelu (in-place on h1)
    gat1_attn_kernel<<<dim3(16384), blk, 0, stream>>>(h1, miss, g1_al, g1_ar, g1_b);

    // 4) gat2 linear: h2[65536,256] = x1[65536,512] @ g2_W^T
    gemm_nt_mfma<0, false><<<dim3(2, 512, 1), blk, 0, stream>>>(
        H14, G2W, NUL, h2, 512, 512, 256, 0);

    // 5) gat2 attention + pool + layernorm -> normed[16384,256]
    gat2_attn_kernel<<<dim3(4096), blk, 0, stream>>>(
        h2, miss, g2_al, g2_ar, g2_b, ln_g, ln_b, normed);

    // 6) head1: hid = relu(normed @ h_W1^T + h_b1)
    gemm_nt_mfma<1, true><<<dim3(2, 128, 1), blk, 0, stream>>>(
        N4, HW1, HB1, hid, 256, 256, 256, 0);

    // 7) head2: out[16384,8]
    head2_kernel<<<dim3(512), blk, 0, stream>>>(hid, h_W2, h_b2, out);
}

// Round 14
// 376.347 us; speedup vs baseline: 1.1303x; 1.0775x over previous
//
#include <hip/hip_runtime.h>

// B=16384, FEAT=1024, FD=256, M=4 nodes, H1=4x128 (concat->512), H2=1x256, OUT=8.
// Round 14: r13 base (best, 405us) + ONE coherent change: attention kernels'
// VALU diet — expf->__expf (native) in softmax/sigmoid, and 24->18 butterfly
// values (symmetric-logit dedup; surviving values bit-identical).

typedef __attribute__((ext_vector_type(8))) _Float16 f16x8;
typedef __attribute__((ext_vector_type(4))) float f32x4;

struct P4 { const float* p[4]; };

#define SYM(i,j) ((i)*(7-(i))/2 + (j))   // unique symmetric index, i<=j

__device__ __forceinline__ float sigmoidf_(float x) { return 1.0f / (1.0f + __expf(-x)); }
__device__ __forceinline__ float gelu_(float x) {
    return 0.5f * x * (1.0f + erff(x * 0.70710678118654752440f));
}

// ---------------- fp16-MFMA NT GEMM (round-13 verbatim) ----------------------
// Schedule per iter k: [ds_write tile k+1 (regs from iter k-1)] ->
//                      [issue loads tile k+2] -> [MFMA buf k] -> [barrier]
template<int ACT, bool HAS_BIAS>
__global__ __launch_bounds__(256)
void gemm_nt_mfma(P4 A4, P4 W4, P4 b4, float* __restrict__ C,
                  int K, int lda, int ldc, int zofs)
{
    __shared__ __align__(16) _Float16 As[2][128][32];
    __shared__ __align__(16) _Float16 Bs[2][128][32];
    const int z = blockIdx.z;
    const float* __restrict__ A    = A4.p[z];
    const float* __restrict__ Bw   = W4.p[z];
    const float* __restrict__ bias = b4.p[z];
    float* __restrict__ Cz = C + (long)z * zofs;

    const int t    = threadIdx.x;
    const int lane = t & 63;
    const int w    = t >> 6;
    const int wr   = (w >> 1) << 6;
    const int wc   = (w & 1) << 6;
    const long rowA = (long)blockIdx.y * 128;
    const long colB = (long)blockIdx.x * 128;

    const float* Apt[4];
    const float* Bpt[4];
    int rr[4], cc[4];
    #pragma unroll
    for (int i = 0; i < 4; ++i) {
        const int f = t + i * 256;
        rr[i] = f >> 3;
        cc[i] = (f & 7) << 2;
        Apt[i] = A  + (rowA + rr[i]) * (long)lda + cc[i];
        Bpt[i] = Bw + (colB + rr[i]) * (long)K   + cc[i];
    }

    f32x4 acc[4][4] = {};
    const int NK = K >> 5;

    float4 aP[4], bP[4], aN[4], bN[4];
    #pragma unroll
    for (int i = 0; i < 4; ++i) {
        aP[i] = *(const float4*)(Apt[i]);
        bP[i] = *(const float4*)(Bpt[i]);
    }
    #pragma unroll
    for (int i = 0; i < 4; ++i) {
        union { _Float16 h[4]; uint2 u; } pa, pb;
        pa.h[0] = (_Float16)aP[i].x; pa.h[1] = (_Float16)aP[i].y;
        pa.h[2] = (_Float16)aP[i].z; pa.h[3] = (_Float16)aP[i].w;
        pb.h[0] = (_Float16)bP[i].x; pb.h[1] = (_Float16)bP[i].y;
        pb.h[2] = (_Float16)bP[i].z; pb.h[3] = (_Float16)bP[i].w;
        *(uint2*)&As[0][rr[i]][cc[i]] = pa.u;
        *(uint2*)&Bs[0][rr[i]][cc[i]] = pb.u;
    }
    if (NK > 1) {
        #pragma unroll
        for (int i = 0; i < 4; ++i) {
            aP[i] = *(const float4*)(Apt[i] + 32);
            bP[i] = *(const float4*)(Bpt[i] + 32);
        }
    }
    __syncthreads();

    const int fr = lane & 15;
    const int fg = (lane >> 4) << 3;

    for (int kk = 0; kk < NK; ++kk) {
        const int cur = kk & 1, nxt = cur ^ 1;

        if (kk + 1 < NK) {
            #pragma unroll
            for (int i = 0; i < 4; ++i) {
                union { _Float16 h[4]; uint2 u; } pa, pb;
                pa.h[0] = (_Float16)aP[i].x; pa.h[1] = (_Float16)aP[i].y;
                pa.h[2] = (_Float16)aP[i].z; pa.h[3] = (_Float16)aP[i].w;
                pb.h[0] = (_Float16)bP[i].x; pb.h[1] = (_Float16)bP[i].y;
                pb.h[2] = (_Float16)bP[i].z; pb.h[3] = (_Float16)bP[i].w;
                *(uint2*)&As[nxt][rr[i]][cc[i]] = pa.u;
                *(uint2*)&Bs[nxt][rr[i]][cc[i]] = pb.u;
            }
        }

        if (kk + 2 < NK) {
            const int ko = (kk + 2) << 5;
            #pragma unroll
            for (int i = 0; i < 4; ++i) {
                aN[i] = *(const float4*)(Apt[i] + ko);
                bN[i] = *(const float4*)(Bpt[i] + ko);
            }
        }

        f16x8 af[4], bf[4];
        #pragma unroll
        for (int m = 0; m < 4; ++m) af[m] = *(const f16x8*)&As[cur][wr + m*16 + fr][fg];
        #pragma unroll
        for (int n = 0; n < 4; ++n) bf[n] = *(const f16x8*)&Bs[cur][wc + n*16 + fr][fg];
        #pragma unroll
        for (int m = 0; m < 4; ++m)
            #pragma unroll
            for (int n = 0; n < 4; ++n)
                acc[m][n] = __builtin_amdgcn_mfma_f32_16x16x32_f16(af[m], bf[n], acc[m][n], 0, 0, 0);

        __syncthreads();
        if (kk + 2 < NK) {
            #pragma unroll
            for (int i = 0; i < 4; ++i) { aP[i] = aN[i]; bP[i] = bN[i]; }
        }
    }

    const int fq = lane >> 4;
    #pragma unroll
    for (int n = 0; n < 4; ++n) {
        const long col = colB + wc + n*16 + fr;
        const float bn = HAS_BIAS ? bias[col] : 0.0f;
        #pragma unroll
        for (int m = 0; m < 4; ++m) {
            const long row0 = rowA + wr + m*16 + fq*4;
            #pragma unroll
            for (int j = 0; j < 4; ++j) {
                float x = acc[m][n][j] + bn;
                if (ACT == 1) x = fmaxf(x, 0.0f);
                Cz[(row0 + j) * (long)ldc + col] = x;
            }
        }
    }
}

// ---------------- GAT1 attention: one wave per (b,h); 18-value butterfly -----
// Each surviving red value is the bit-identical expression/tree from r13;
// the 6 dropped values were exact duplicates (logits symmetric).
__global__ __launch_bounds__(256)
void gat1_attn_kernel(float* __restrict__ h1,
                      const int* __restrict__ missing,
                      const float* __restrict__ attl, const float* __restrict__ attr,
                      const float* __restrict__ bias)
{
    const int gtid = blockIdx.x * 256 + threadIdx.x;
    const int wid  = gtid >> 6;
    const int lane = threadIdx.x & 63;
    const int b = wid >> 2;
    const int h = wid & 3;
    const int cb = h * 128 + lane;
    float* base = h1 + (size_t)b * 2048 + cb;

    float hr[4][2];
    #pragma unroll
    for (int j = 0; j < 4; ++j) { hr[j][0] = base[j*512]; hr[j][1] = base[j*512 + 64]; }
    const float al0 = attl[cb], al1 = attl[cb+64];
    const float ar0 = attr[cb], ar1 = attr[cb+64];

    float red[18];
    #pragma unroll
    for (int i = 0; i < 4; ++i)
        #pragma unroll
        for (int j = i; j < 4; ++j)
            red[SYM(i,j)] = hr[i][0]*hr[j][0] + hr[i][1]*hr[j][1];
    #pragma unroll
    for (int j = 0; j < 4; ++j) {
        red[10+j] = hr[j][0]*al0 + hr[j][1]*al1;
        red[14+j] = hr[j][0]*ar0 + hr[j][1]*ar1;
    }
    #pragma unroll
    for (int m = 1; m < 64; m <<= 1)
        #pragma unroll
        for (int r = 0; r < 18; ++r)
            red[r] += __shfl_xor(red[r], m, 64);

    const int miss = missing[b];
    bool pres[4];
    #pragma unroll
    for (int mm = 0; mm < 4; ++mm) pres[mm] = (miss != mm + 1);

    float attn[4][4];
    #pragma unroll
    for (int i = 0; i < 4; ++i) {
        float av[4]; float mx = -3.4e38f;
        #pragma unroll
        for (int j = 0; j < 4; ++j) {
            const bool mk = (i == j) || (pres[i] && pres[j]);
            const float l = (i <= j) ? red[SYM(i,j)] : red[SYM(j,i)];
            float v = (red[14+i] + red[10+j]) * sigmoidf_(l);
            v = (v >= 0.0f) ? v : 0.2f * v;
            av[j] = mk ? v : -1e30f;
            mx = fmaxf(mx, av[j]);
        }
        float den = 0.0f;
        #pragma unroll
        for (int j = 0; j < 4; ++j) { av[j] = __expf(av[j] - mx); den += av[j]; }
        const float inv = 1.0f / den;
        #pragma unroll
        for (int j = 0; j < 4; ++j) attn[i][j] = av[j] * inv;
    }

    const float b0 = bias[cb], b1 = bias[cb+64];
    #pragma unroll
    for (int i = 0; i < 4; ++i) {
        float o0 = b0, o1 = b1;
        #pragma unroll
        for (int j = 0; j < 4; ++j) { o0 += attn[i][j]*hr[j][0]; o1 += attn[i][j]*hr[j][1]; }
        base[i*512]      = gelu_(o0);
        base[i*512 + 64] = gelu_(o1);
    }
}

// ------- GAT2 attention + pool + LayerNorm: 18-value butterfly, __expf -------
__global__ __launch_bounds__(256)
void gat2_attn_kernel(const float* __restrict__ h2,
                      const int* __restrict__ missing,
                      const float* __restrict__ attl, const float* __restrict__ attr,
                      const float* __restrict__ bias,
                      const float* __restrict__ lng, const float* __restrict__ lnb,
                      float* __restrict__ normed)
{
    const int gtid = blockIdx.x * 256 + threadIdx.x;
    const int b = gtid >> 6;
    const int lane = threadIdx.x & 63;
    const float4* hp = (const float4*)(h2 + (size_t)b * 1024);

    float4 hr[4];
    #pragma unroll
    for (int j = 0; j < 4; ++j) hr[j] = hp[j*64 + lane];
    const float4 al = ((const float4*)attl)[lane];
    const float4 ar = ((const float4*)attr)[lane];

    float red[18];
    #pragma unroll
    for (int i = 0; i < 4; ++i)
        #pragma unroll
        for (int j = i; j < 4; ++j)
            red[SYM(i,j)] = hr[i].x*hr[j].x + hr[i].y*hr[j].y + hr[i].z*hr[j].z + hr[i].w*hr[j].w;
    #pragma unroll
    for (int j = 0; j < 4; ++j) {
        red[10+j] = hr[j].x*al.x + hr[j].y*al.y + hr[j].z*al.z + hr[j].w*al.w;
        red[14+j] = hr[j].x*ar.x + hr[j].y*ar.y + hr[j].z*ar.z + hr[j].w*ar.w;
    }
    #pragma unroll
    for (int m = 1; m < 64; m <<= 1)
        #pragma unroll
        for (int r = 0; r < 18; ++r)
            red[r] += __shfl_xor(red[r], m, 64);

    const int miss = missing[b];
    bool pres[4];
    #pragma unroll
    for (int mm = 0; mm < 4; ++mm) pres[mm] = (miss != mm + 1);

    float wsum[4] = {0.f, 0.f, 0.f, 0.f};
    #pragma unroll
    for (int i = 0; i < 4; ++i) {
        float av[4]; float mx = -3.4e38f;
        #pragma unroll
        for (int j = 0; j < 4; ++j) {
            const bool mk = (i == j) || (pres[i] && pres[j]);
            const float l = (i <= j) ? red[SYM(i,j)] : red[SYM(j,i)];
            float v = (red[14+i] + red[10+j]) * sigmoidf_(l);
            v = (v >= 0.0f) ? v : 0.2f * v;
            av[j] = mk ? v : -1e30f;
            mx = fmaxf(mx, av[j]);
        }
        float den = 0.0f;
        #pragma unroll
        for (int j = 0; j < 4; ++j) { av[j] = __expf(av[j] - mx); den += av[j]; }
        const float inv = 0.25f / den;
        #pragma unroll
        for (int j = 0; j < 4; ++j) wsum[j] += av[j] * inv;
    }

    const float4 bv = ((const float4*)bias)[lane];
    float pooled[4] = {bv.x, bv.y, bv.z, bv.w};
    #pragma unroll
    for (int j = 0; j < 4; ++j) {
        pooled[0] += wsum[j] * hr[j].x;
        pooled[1] += wsum[j] * hr[j].y;
        pooled[2] += wsum[j] * hr[j].z;
        pooled[3] += wsum[j] * hr[j].w;
    }

    float s1 = pooled[0] + pooled[1] + pooled[2] + pooled[3];
    float s2 = pooled[0]*pooled[0] + pooled[1]*pooled[1] + pooled[2]*pooled[2] + pooled[3]*pooled[3];
    #pragma unroll
    for (int m = 1; m < 64; m <<= 1) {
        s1 += __shfl_xor(s1, m, 64);
        s2 += __shfl_xor(s2, m, 64);
    }
    const float mu   = s1 * (1.0f / 256.0f);
    const float var  = s2 * (1.0f / 256.0f) - mu * mu;
    const float rstd = rsqrtf(var + 1e-5f);
    const float4 g  = ((const float4*)lng)[lane];
    const float4 bb = ((const float4*)lnb)[lane];
    float4 o;
    o.x = (pooled[0] - mu) * rstd * g.x + bb.x;
    o.y = (pooled[1] - mu) * rstd * g.y + bb.y;
    o.z = (pooled[2] - mu) * rstd * g.z + bb.z;
    o.w = (pooled[3] - mu) * rstd * g.w + bb.w;
    ((float4*)normed)[(size_t)b * 64 + lane] = o;
}

// ---------------- head2 (round-4 verbatim) ----------------------------------
__global__ __launch_bounds__(256)
void head2_kernel(const float* __restrict__ hid, const float* __restrict__ W2,
                  const float* __restrict__ b2, float* __restrict__ out)
{
    const int t = blockIdx.x * 256 + threadIdx.x;
    const int b = t >> 3, o = t & 7;
    const float4* hp = (const float4*)(hid + (size_t)b * 256);
    const float4* wp = (const float4*)(W2 + o * 256);
    float acc = b2[o];
    #pragma unroll 8
    for (int c = 0; c < 64; ++c) {
        const float4 hv = hp[c], wv = wp[c];
        acc += hv.x*wv.x + hv.y*wv.y + hv.z*wv.z + hv.w*wv.w;
    }
    out[t] = acc;
}

// ---------------- launch (round-4 verbatim) ---------------------------------
extern "C" void kernel_launch(void* const* d_in, const int* in_sizes, int n_in,
                              void* d_out, int out_size, void* d_ws, size_t ws_size,
                              hipStream_t stream)
{
    (void)in_sizes; (void)n_in; (void)out_size; (void)ws_size;
    const float* X0 = (const float*)d_in[0];
    const float* X1 = (const float*)d_in[1];
    const float* X2 = (const float*)d_in[2];
    const float* X3 = (const float*)d_in[3];
    const int*   miss  = (const int*)d_in[4];
    const float* g1_W  = (const float*)d_in[13];
    const float* g1_al = (const float*)d_in[14];
    const float* g1_ar = (const float*)d_in[15];
    const float* g1_b  = (const float*)d_in[16];
    const float* g2_W  = (const float*)d_in[17];
    const float* g2_al = (const float*)d_in[18];
    const float* g2_ar = (const float*)d_in[19];
    const float* g2_b  = (const float*)d_in[20];
    const float* ln_g  = (const float*)d_in[21];
    const float* ln_b  = (const float*)d_in[22];
    const float* h_W1  = (const float*)d_in[23];
    const float* h_b1  = (const float*)d_in[24];
    const float* h_W2  = (const float*)d_in[25];
    const float* h_b2  = (const float*)d_in[26];
    float* out = (float*)d_out;

    float* ws     = (float*)d_ws;
    float* feats  = ws;
    float* h1     = ws + 16777216;
    float* h2     = ws;
    float* normed = ws + 16777216;
    float* hid    = normed + 4194304;

    const dim3 blk(256);

    P4 Xs  = {{X0, X1, X2, X3}};
    P4 Wms = {{(const float*)d_in[5], (const float*)d_in[7],
               (const float*)d_in[9], (const float*)d_in[11]}};
    P4 bms = {{(const float*)d_in[6], (const float*)d_in[8],
               (const float*)d_in[10], (const float*)d_in[12]}};
    P4 F4  = {{feats, feats, feats, feats}};
    P4 G1W = {{g1_W, g1_W, g1_W, g1_W}};
    P4 H14 = {{h1, h1, h1, h1}};
    P4 G2W = {{g2_W, g2_W, g2_W, g2_W}};
    P4 N4  = {{normed, normed, normed, normed}};
    P4 HW1 = {{h_W1, h_W1, h_W1, h_W1}};
    P4 HB1 = {{h_b1, h_b1, h_b1, h_b1}};
    P4 NUL = {{nullptr, nullptr, nullptr, nullptr}};

    // 1) per-modality projections (z-batched): feats[B,4,256]
    gemm_nt_mfma<0, true><<<dim3(2, 128, 4), blk, 0, stream>>>(
        Xs, Wms, bms, feats, /*K=*/1024, /*lda=*/1024, /*ldc=*/1024, /*zofs=*/256);

    // 2) gat1 linear: h1[65536,512] = feats[65536,256] @ g1_W^T
    gemm_nt_mfma<0, false><<<dim3(4, 512, 1), blk, 0, stream>>>(
        F4, G1W, NUL, h1, 256, 256, 512, 0);

    // 3) gat1 attention + bias + gelu (in-place on h1)
    gat1_attn_kernel<<<dim3(16384), blk, 0, stream>>>(h1, miss, g1_al, g1_ar, g1_b);

    // 4) gat2 linear: h2[65536,256] = x1[65536,512] @ g2_W^T
    gemm_nt_mfma<0, false><<<dim3(2, 512, 1), blk, 0, stream>>>(
        H14, G2W, NUL, h2, 512, 512, 256, 0);

    // 5) gat2 attention + pool + layernorm -> normed[16384,256]
    gat2_attn_kernel<<<dim3(4096), blk, 0, stream>>>(
        h2, miss, g2_al, g2_ar, g2_b, ln_g, ln_b, normed);

    // 6) head1: hid = relu(normed @ h_W1^T + h_b1)
    gemm_nt_mfma<1, true><<<dim3(2, 128, 1), blk, 0, stream>>>(
        N4, HW1, HB1, hid, 256, 256, 256, 0);

    // 7) head2: out[16384,8]
    head2_kernel<<<dim3(512), blk, 0, stream>>>(hid, h_W2, h_b2, out);
}